// Round 1
// 411.397 us; speedup vs baseline: 1.0375x; 1.0375x over previous
//
#include <hip/hip_runtime.h>

#define ROWS 16384
#define COLS 4096
#define KSEL 512
#define THREADS 256
#define NCOPY0 8       // pass-0 histogram copies (hot bins from normal data)
#define HSTRIDE 260    // words per copy: bank-skewed (260%32==4), 16B-aligned
#define HWORDS ((NCOPY0 + 3) * HSTRIDE)
// regions: [0..NCOPY0): pass-0 copies; NCOPY0: pass-1 hist;
// NCOPY0+1: candidate pool (64 slots + count)  OR fallback pass-2 hist (disjoint paths);
// NCOPY0+2: fallback pass-3 hist.
// LDS: 11 * 260 * 4 = 11440 B -> 8 blocks/CU uses 89 KB of 160 KB

typedef float    f32x4 __attribute__((ext_vector_type(4)));
typedef unsigned u32x4 __attribute__((ext_vector_type(4)));

// order-preserving float->uint map: compare as unsigned == compare as float
__device__ __forceinline__ unsigned map_f(float f) {
    unsigned u = __float_as_uint(f);
    return u ^ (0x80000000u | (unsigned)((int)u >> 31));
}
__device__ __forceinline__ float unmap_f(unsigned m) {
    return __uint_as_float(m ^ (0x80000000u | ~(unsigned)((int)m >> 31)));
}

// wave-redundant digit select: lane owns bins [4*lane .. 4*lane+3] with counts
// n0..n3; suffix-scan across the wave locates the digit containing rank kk.
// Also returns cnt = population of the selected digit (enables direct ranking).
__device__ __forceinline__ void select_digit(unsigned n0, unsigned n1, unsigned n2,
                                             unsigned n3, int lane, int shift,
                                             unsigned& prefix, unsigned& kk,
                                             unsigned& cnt) {
    unsigned ls3 = n3, ls2 = n3 + n2, ls1 = ls2 + n1, tot = ls1 + n0;
    unsigned S = tot;
#pragma unroll
    for (int off = 1; off < 64; off <<= 1) {
        unsigned o = __shfl(S, lane + off);
        S += (lane + off < 64) ? o : 0u;
    }
    const unsigned R = S - tot;  // count with digit >= 4*(lane+1)
    const unsigned S3 = R + ls3, S2 = R + ls2, S1 = R + ls1, S0 = R + tot;
    unsigned dig = 0, nk = 0, cn = 0;
    bool found = false;
    if (S3 >= kk && R  < kk) { dig = 4 * lane + 3; nk = kk - R;  cn = n3; found = true; }
    if (S2 >= kk && S3 < kk) { dig = 4 * lane + 2; nk = kk - S3; cn = n2; found = true; }
    if (S1 >= kk && S2 < kk) { dig = 4 * lane + 1; nk = kk - S2; cn = n1; found = true; }
    if (S0 >= kk && S1 < kk) { dig = 4 * lane + 0; nk = kk - S1; cn = n0; found = true; }
    unsigned long long m = __ballot(found);
    int src = (int)__ffsll(m) - 1;
    prefix |= (unsigned)__shfl(dig, src) << shift;
    kk  = (unsigned)__shfl(nk, src);
    cnt = (unsigned)__shfl(cn, src);
}

__global__ __launch_bounds__(THREADS, 8) void kwta_kernel(const float* __restrict__ in,
                                                          float* __restrict__ out) {
    __shared__ __align__(16) unsigned hist[HWORDS];

    const int tid  = threadIdx.x;
    const int lane = tid & 63;
    const int row  = blockIdx.x;

    const f32x4* __restrict__ inrow  = (const f32x4*)(in  + (size_t)row * COLS);
    f32x4*       __restrict__ outrow = (f32x4*)(out + (size_t)row * COLS);

    // 16 elements per thread, coalesced nontemporal float4 loads, mapped in place
    unsigned v[16];
#pragma unroll
    for (int i = 0; i < 4; i++) {
        f32x4 f = __builtin_nontemporal_load(inrow + tid + THREADS * i);
        v[4 * i + 0] = map_f(f.x);
        v[4 * i + 1] = map_f(f.y);
        v[4 * i + 2] = map_f(f.z);
        v[4 * i + 3] = map_f(f.w);
    }

    // zero all histogram buffers + pool count once (single hazard barrier)
    {
        const u32x4 z = {0u, 0u, 0u, 0u};
#pragma unroll
        for (int i = 0; i < 3; i++) {
            int w4 = tid + THREADS * i;
            if (w4 < HWORDS / 4) ((u32x4*)hist)[w4] = z;
        }
    }
    __syncthreads();

    unsigned prefix = 0;  // selected high bits (mapped space)
    unsigned kk = KSEL;
    unsigned cnt = 0;

    // ---- pass 0: top byte, 8-copy histogram (contention-spread) ----
    {
        unsigned* h0 = hist + (tid & (NCOPY0 - 1)) * HSTRIDE;
#pragma unroll
        for (int i = 0; i < 16; i++) atomicAdd(&h0[v[i] >> 24], 1u);
        __syncthreads();
        unsigned n0 = 0, n1 = 0, n2 = 0, n3 = 0;
#pragma unroll
        for (int c = 0; c < NCOPY0; c++) {
            u32x4 t = ((const u32x4*)(hist + c * HSTRIDE))[lane];
            n0 += t.x; n1 += t.y; n2 += t.z; n3 += t.w;
        }
        select_digit(n0, n1, n2, n3, lane, 24, prefix, kk, cnt);
    }

    // ---- pass 1: bits 23..16, private single-copy buffer ----
    {
        unsigned* hp = hist + NCOPY0 * HSTRIDE;
#pragma unroll
        for (int i = 0; i < 16; i++) {
            if (((v[i] ^ prefix) >> 24) == 0u)
                atomicAdd(&hp[(v[i] >> 16) & 255u], 1u);
        }
        __syncthreads();
        u32x4 t = ((const u32x4*)hp)[lane];
        select_digit(t.x, t.y, t.z, t.w, lane, 16, prefix, kk, cnt);
    }

    unsigned thresh;
    // For N(0,1) rows the selected 16-bit bin holds ~7 elements: rank them
    // directly instead of running two more histogram passes. (cnt, kk, prefix
    // are block-uniform -> branch + barriers inside are uniform.)
    if (cnt <= 64u) {
        unsigned* pool   = hist + (NCOPY0 + 1) * HSTRIDE;
        unsigned* pcount = pool + 64;
#pragma unroll
        for (int i = 0; i < 16; i++) {
            if (((v[i] ^ prefix) >> 16) == 0u) {
                unsigned slot = atomicAdd(pcount, 1u);
                pool[slot] = v[i];
            }
        }
        __syncthreads();
        // wave-redundant all-pairs rank: threshold is the value with
        // (#greater < kk) && (#greater + #equal >= kk)
        unsigned x = (lane < (int)cnt) ? pool[lane] : 0u;
        unsigned g = 0, e = 0;
        for (unsigned j = 0; j < cnt; j++) {
            unsigned y = pool[j];  // same address all lanes -> LDS broadcast
            g += (y > x) ? 1u : 0u;
            e += (y == x) ? 1u : 0u;
        }
        bool found = (lane < (int)cnt) && (g < kk) && (g + e >= kk);
        unsigned long long m = __ballot(found);
        int src = (int)__ffsll(m) - 1;
        thresh = (unsigned)__shfl(x, src);
    } else {
        // fallback (pathological rows only): exact passes 2..3 as before
#pragma unroll
        for (int pass = 2; pass < 4; pass++) {
            const int shift = 24 - 8 * pass;
            const int hs = shift + 8;
            unsigned* hp = hist + (NCOPY0 + pass - 1) * HSTRIDE;
#pragma unroll
            for (int i = 0; i < 16; i++) {
                if (((v[i] ^ prefix) >> hs) == 0u)
                    atomicAdd(&hp[(v[i] >> shift) & 255u], 1u);
            }
            __syncthreads();
            u32x4 t = ((const u32x4*)hp)[lane];
            select_digit(t.x, t.y, t.z, t.w, lane, shift, prefix, kk, cnt);
        }
        thresh = prefix;
    }

    // thresh == mapped bit pattern of the exact K-th largest; compare in mapped space
#pragma unroll
    for (int i = 0; i < 4; i++) {
        f32x4 o;
        o.x = (v[4 * i + 0] >= thresh) ? unmap_f(v[4 * i + 0]) : 0.0f;
        o.y = (v[4 * i + 1] >= thresh) ? unmap_f(v[4 * i + 1]) : 0.0f;
        o.z = (v[4 * i + 2] >= thresh) ? unmap_f(v[4 * i + 2]) : 0.0f;
        o.w = (v[4 * i + 3] >= thresh) ? unmap_f(v[4 * i + 3]) : 0.0f;
        __builtin_nontemporal_store(o, outrow + tid + THREADS * i);
    }
}

extern "C" void kernel_launch(void* const* d_in, const int* in_sizes, int n_in,
                              void* d_out, int out_size, void* d_ws, size_t ws_size,
                              hipStream_t stream) {
    const float* s = (const float*)d_in[0];
    float* out = (float*)d_out;
    kwta_kernel<<<ROWS, THREADS, 0, stream>>>(s, out);
}